// Round 7
// baseline (2361.443 us; speedup 1.0000x reference)
//
#include <hip/hip_runtime.h>
#include <hip/hip_bf16.h>

#define BSZ    256
#define SEQT   2048
#define NVOCAB 10
#define DEMB   32
#define G4     256
#define BLK    320   // 5 waves: 0 = recurrence (BOTH chains); 1..4 = MLP

typedef unsigned short u16;
typedef unsigned int   u32;
typedef float    v4f __attribute__((ext_vector_type(4)));
typedef u32      v4u __attribute__((ext_vector_type(4)));
typedef _Float16 v2h __attribute__((ext_vector_type(2)));

// ws layout (float slots; some regions hold u32 f16-pair bits)
#define FLAG_OFF 0
#define XZ4_OFF  4                      // [10 v][64 j][4 g] f32 = 2560 (16B aligned)
#define WHP_OFF  (XZ4_OFF + 2560)      // u32 [64 l][4 g][32 kpair] = 8192
#define W1P_OFF  (WHP_OFF + 8192)      // u32 [64 o][64 kpair] = 4096
#define W2P_OFF  (W1P_OFF + 4096)      // u32 [32 o][32 kpair] = 1024
#define W3_OFF   (W2P_OFF + 1024)      // f32 [32][10] = 320
#define B1_OFF   (W3_OFF + 320)
#define B2_OFF   (B1_OFF + 64)
#define B3_OFF   (B2_OFF + 32)

__device__ __forceinline__ float bf2f(u16 x) {
    union { u32 u; float f; } v; v.u = ((u32)x) << 16; return v.f;
}
__device__ __forceinline__ u16 f2bf(float f) {
    union { float f; u32 u; } v; v.f = f;
    u32 r = v.u + 0x7fff + ((v.u >> 16) & 1);
    return (u16)(r >> 16);
}
__device__ __forceinline__ float ldw(const void* p, int i, bool isbf) {
    return isbf ? bf2f(((const u16*)p)[i]) : ((const float*)p)[i];
}
__device__ __forceinline__ float frcp(float x) { return __builtin_amdgcn_rcpf(x); }
__device__ __forceinline__ float sigf(float z) { return frcp(1.f + __expf(-z)); }  // inf-safe
__device__ __forceinline__ u16 f2h(float x) {
    union { _Float16 h; u16 u; } v; v.h = (_Float16)x; return v.u;
}
__device__ __forceinline__ u32 packh2(float lo, float hi) {
    return (u32)f2h(lo) | ((u32)f2h(hi) << 16);
}
__device__ __forceinline__ float fdot2f(u32 a, u32 b, float c) {
    union { u32 u; v2h h; } ua, ub; ua.u = a; ub.u = b;
    return __builtin_amdgcn_fdot2(ua.h, ub.h, c, false);
}
// 4 f16-pair dots: acc += w.h (8 MACs), f32 accumulation
__device__ __forceinline__ void dot4(float& acc, v4u w, v4u h) {
    acc = fdot2f(w.x, h.x, acc); acc = fdot2f(w.y, h.y, acc);
    acc = fdot2f(w.z, h.z, acc); acc = fdot2f(w.w, h.w, acc);
}

// One-time prep: dtype detect, xz float4 table (E@Wx+b: 10 rows), per-lane
// f16-packed Wh table, f16-packed MLP weights.  (unchanged)
__global__ void init_kernel(const void* __restrict__ E,  const void* __restrict__ Wx,
                            const void* __restrict__ Wh, const void* __restrict__ bg,
                            const void* __restrict__ W1, const void* __restrict__ b1,
                            const void* __restrict__ W2, const void* __restrict__ b2,
                            const void* __restrict__ W3, const void* __restrict__ b3,
                            float* __restrict__ ws) {
    __shared__ int s_isbf;
    const int tid = threadIdx.x;  // 256 threads, 1 block
    if (tid == 0) s_isbf = 1;
    __syncthreads();
    {   // bf16 data decodes small; fp32 low-halves decode wild exponents
        const u16* Eu = (const u16*)E;
        for (int i = tid; i < NVOCAB * DEMB; i += 256) {
            float v = bf2f(Eu[i]);
            if (!(fabsf(v) < 16.0f)) s_isbf = 0;
        }
    }
    __syncthreads();
    const bool isbf = (s_isbf != 0);
    if (tid == 0) ws[FLAG_OFF] = isbf ? 1.0f : 0.0f;
    u32* wsu = (u32*)ws;

    {   // xz[v][j][g] = b[g*64+j] + sum_d E[v][d]*Wx[d][g*64+j]
        const int g = tid >> 6, j = tid & 63, col = g * 64 + j;
        for (int v = 0; v < NVOCAB; v++) {
            float acc = ldw(bg, col, isbf);
            #pragma unroll
            for (int d = 0; d < DEMB; d++)
                acc += ldw(E, v * DEMB + d, isbf) * ldw(Wx, d * G4 + col, isbf);
            ws[XZ4_OFF + (v * 64 + j) * 4 + g] = acc;
        }
    }
    // Wh per-lane table: u32[l*128 + g*32 + kk] = pack(Wh[2kk][g*64+l], Wh[2kk+1][g*64+l])
    for (int i = tid; i < 8192; i += 256) {
        int l = i >> 7, rem = i & 127, g = rem >> 5, kk = rem & 31;
        int col = g * 64 + l;
        wsu[WHP_OFF + i] = packh2(ldw(Wh, (2 * kk) * G4 + col, isbf),
                                  ldw(Wh, (2 * kk + 1) * G4 + col, isbf));
    }
    for (int i = tid; i < 4096; i += 256) {   // W1 [128][64] -> [o][kpair] f16x2
        int o = i >> 6, kk = i & 63;
        wsu[W1P_OFF + i] = packh2(ldw(W1, (2 * kk) * 64 + o, isbf),
                                  ldw(W1, (2 * kk + 1) * 64 + o, isbf));
    }
    for (int i = tid; i < 1024; i += 256) {   // W2 [64][32] -> [o][kpair]
        int o = i >> 5, kk = i & 31;
        wsu[W2P_OFF + i] = packh2(ldw(W2, (2 * kk) * 32 + o, isbf),
                                  ldw(W2, (2 * kk + 1) * 32 + o, isbf));
    }
    for (int i = tid; i < 320; i += 256) ws[W3_OFF + i] = ldw(W3, i, isbf);
    if (tid < 64) ws[B1_OFF + tid] = ldw(b1, tid, isbf);
    if (tid < 32) ws[B2_OFF + tid] = ldw(b2, tid, isbf);
    if (tid < NVOCAB) ws[B3_OFF + tid] = ldw(b3, tid, isbf);
}

// One block (320 thr, 5 waves) per batch element.
//   wave 0 = recurrence, BOTH chains fused (they share Wh!);
//   waves 1..4 = MLP, 8 tokens each.
// Fusing both chains into one wave: (a) each weight quad is loaded once
// and used twice back-to-back -> if the allocator's AGPR demotion forces
// per-use shuttles, their cost is halved per chain; (b) the two chains'
// dependency chains (h-roundtrip ~120cy, gate exp/rcp chains ~100cy) are
// independent -> one chain's dots fill the other's latency bubbles.
// h-quad-outermost loop keeps only 2 h quads live (reg pressure ~180).
// DS/step: 16 broadcast b128 + 2 strided b128 + 2 b16 writes ~ 100 cyc
// << 512 cyc VALU issue -> not DS-bound (R6's failure mode).
__global__ __launch_bounds__(BLK) void lstm_fused(
    const int* __restrict__ num1, const int* __restrict__ num2,
    const float* __restrict__ ws, void* __restrict__ outv)
{
    __shared__ __align__(16) float xz4s[2560];          // 10240 B
    __shared__ __align__(16) u16 hwinh[2][32][128];     // 16384 B (f16 h, dbuf window)
    __shared__ __align__(16) u32 W1p[64 * 68];          // 17408 B
    __shared__ __align__(16) u32 W2p[32 * 36];          //  4608 B
    __shared__ float W3s[320];                          //  1280 B
    __shared__ __align__(16) u16 w1h[32 * 72];          //  4608 B
    __shared__ __align__(16) float w2buf[32 * 36];      //  4608 B
    __shared__ int idxs[2][2][32];                      //   512 B  -> ~59.6 KB

    const int tid = threadIdx.x, bb = blockIdx.x;
    const int wv = tid >> 6, l = tid & 63;
    const u32* wsu = (const u32*)ws;
    const bool outbf = (ws[FLAG_OFF] != 0.0f);

    for (int i = tid; i < 2560; i += BLK) xz4s[i] = ws[XZ4_OFF + i];
    for (int i = tid; i < 4096; i += BLK) { int o = i >> 6, kk = i & 63; W1p[o * 68 + kk] = wsu[W1P_OFF + i]; }
    for (int i = tid; i < 1024; i += BLK) { int o = i >> 5, kk = i & 31; W2p[o * 36 + kk] = wsu[W2P_OFF + i]; }
    for (int i = tid; i < 320; i += BLK) W3s[i] = ws[W3_OFF + i];
    if (tid < 128) hwinh[1][31][tid] = 0;               // h_{-1} = 0 (f16 zero)
    if (tid < 64) { int c0 = tid >> 5, tt = tid & 31;
                    idxs[0][c0][tt] = (c0 == 0 ? num1 : num2)[bb * SEQT + tt]; }

    if (wv == 0) {
        // -------- recurrence wave: both chains, lane l = unit --------
        v4u whq[32];                                    // 128 VGPR-worth of f16-pair Wh
        {
            const v4u* whsrc = (const v4u*)(wsu + WHP_OFF) + (size_t)l * 32;
            #pragma unroll
            for (int i = 0; i < 32; i++) whq[i] = whsrc[i];
        }
        float c0 = 0.f, c1 = 0.f;
        __syncthreads();
        for (int win = 0; win <= 64; win++) {
            #pragma unroll
            for (int i = 0; i < 32; i++) asm("" : "+v"(whq[i]));
            if (win < 64) {
                const int wb = win & 1;
                #pragma unroll 1
                for (int tt = 0; tt < 32; tt++) {
                    const int idx0 = idxs[wb][0][tt];
                    const int idx1 = idxs[wb][1][tt];
                    const int rbuf = (tt == 0) ? 1 - wb : wb;
                    const int rrow = (tt + 31) & 31;
                    const v4u* hp0 = (const v4u*)&hwinh[rbuf][rrow][0];   // broadcast
                    const v4u* hp1 = (const v4u*)&hwinh[rbuf][rrow][64];  // broadcast
                    v4f xzv0 = *(const v4f*)&xz4s[(idx0 * 64 + l) * 4];
                    v4f xzv1 = *(const v4f*)&xz4s[(idx1 * 64 + l) * 4];
                    // chain0 accumulators (lo = h quads 0-3, hi = 4-7)
                    float i0a = 0.f, f0a = 0.f, g0a = 0.f, o0a = 0.f;
                    float i0b = 0.f, f0b = 0.f, g0b = 0.f, o0b = 0.f;
                    // chain1 accumulators
                    float i1a = 0.f, f1a = 0.f, g1a = 0.f, o1a = 0.f;
                    float i1b = 0.f, f1b = 0.f, g1b = 0.f, o1b = 0.f;
                    // h-quad-outermost: 2 h quads live; each weight quad
                    // read once, used for both chains back-to-back.
                    #pragma unroll
                    for (int q = 0; q < 4; q++) {
                        v4u h0 = hp0[q], h1 = hp1[q];
                        dot4(i0a, whq[q],      h0); dot4(i1a, whq[q],      h1);
                        dot4(f0a, whq[8 + q],  h0); dot4(f1a, whq[8 + q],  h1);
                        dot4(g0a, whq[16 + q], h0); dot4(g1a, whq[16 + q], h1);
                        dot4(o0a, whq[24 + q], h0); dot4(o1a, whq[24 + q], h1);
                    }
                    #pragma unroll
                    for (int q = 4; q < 8; q++) {
                        v4u h0 = hp0[q], h1 = hp1[q];
                        dot4(i0b, whq[q],      h0); dot4(i1b, whq[q],      h1);
                        dot4(f0b, whq[8 + q],  h0); dot4(f1b, whq[8 + q],  h1);
                        dot4(g0b, whq[16 + q], h0); dot4(g1b, whq[16 + q], h1);
                        dot4(o0b, whq[24 + q], h0); dot4(o1b, whq[24 + q], h1);
                    }
                    // chain0 tail
                    float zi0 = i0a + i0b + xzv0.x, zf0 = f0a + f0b + xzv0.y;
                    float zg0 = g0a + g0b + xzv0.z, zo0 = o0a + o0b + xzv0.w;
                    // chain1 tail (independent -> interleaves with chain0's)
                    float zi1 = i1a + i1b + xzv1.x, zf1 = f1a + f1b + xzv1.y;
                    float zg1 = g1a + g1b + xzv1.z, zo1 = o1a + o1b + xzv1.w;
                    float gi0 = sigf(zi0), gf0 = sigf(zf0);
                    float gi1 = sigf(zi1), gf1 = sigf(zf1);
                    float gG0 = 2.f * sigf(2.f * zg0) - 1.f, go0 = sigf(zo0);
                    float gG1 = 2.f * sigf(2.f * zg1) - 1.f, go1 = sigf(zo1);
                    c0 = gf0 * c0 + gi0 * gG0;
                    c1 = gf1 * c1 + gi1 * gG1;
                    float th0 = 1.f - 2.f * frcp(__expf(2.f * c0) + 1.f);  // inf-safe tanh
                    float th1 = 1.f - 2.f * frcp(__expf(2.f * c1) + 1.f);
                    hwinh[wb][tt][l]      = f2h(go0 * th0);
                    hwinh[wb][tt][64 + l] = f2h(go1 * th1);
                    // same-wave DS ordering: next step's read needs no barrier
                }
            }
            __syncthreads();
        }
    } else {
        // -------- MLP wave mw = wv-1: tokens [8*mw, 8*mw+8) of previous window ----
        const int mw = wv - 1;
        const int tb = mw * 8;
        const float b1o = ws[B1_OFF + l];
        const int th = l >> 5, o2 = l & 31;
        const float b2o = ws[B2_OFF + o2];
        const int tloc = l / 10, o3 = l - tloc * 10;
        const float b3o = (l < 40) ? ws[B3_OFF + o3] : 0.f;
        u16* outb = (u16*)outv; float* outf = (float*)outv;
        __syncthreads();
        // hoist W3 column into registers (loop-invariant)
        float w3r[32];
        #pragma unroll
        for (int k = 0; k < 32; k++) w3r[k] = (l < 40) ? W3s[k * 10 + o3] : 0.f;
        for (int win = 0; win <= 64; win++) {
            if (win < 63 && mw < 2 && l < 32)   // waves 1,2 prefetch next idx window
                idxs[(win + 1) & 1][mw][l] =
                    (mw == 0 ? num1 : num2)[bb * SEQT + (win + 1) * 32 + l];
            if (win >= 1) {
                const int pw = win - 1, pwb = pw & 1;
                // L1: relu(b1 + hwin[tk][:128] . W1[:,l]), 8 tokens/wave
                float acc[8];
                #pragma unroll
                for (int i = 0; i < 8; i++) acc[i] = b1o;
                for (int kc = 0; kc < 16; kc++) {
                    v4u wq = *(const v4u*)&W1p[l * 68 + 4 * kc];
                    #pragma unroll
                    for (int i = 0; i < 8; i++) {
                        v4u hq = *(const v4u*)&hwinh[pwb][tb + i][8 * kc];
                        float a = acc[i];
                        a = fdot2f(wq.x, hq.x, a); a = fdot2f(wq.y, hq.y, a);
                        a = fdot2f(wq.z, hq.z, a); a = fdot2f(wq.w, hq.w, a);
                        acc[i] = a;
                    }
                }
                #pragma unroll
                for (int i = 0; i < 8; i++)
                    w1h[(tb + i) * 72 + l] = f2h(fmaxf(acc[i], 0.f));
                // L2: own-wave rows, same-wave LDS ordering (no barrier)
                float a2[4];
                #pragma unroll
                for (int i = 0; i < 4; i++) a2[i] = b2o;
                for (int kc = 0; kc < 8; kc++) {
                    v4u wq = *(const v4u*)&W2p[o2 * 36 + 4 * kc];
                    #pragma unroll
                    for (int i = 0; i < 4; i++) {
                        v4u hq = *(const v4u*)&w1h[(tb + th * 4 + i) * 72 + 8 * kc];
                        float a = a2[i];
                        a = fdot2f(wq.x, hq.x, a); a = fdot2f(wq.y, hq.y, a);
                        a = fdot2f(wq.z, hq.z, a); a = fdot2f(wq.w, hq.w, a);
                        a2[i] = a;
                    }
                }
                #pragma unroll
                for (int i = 0; i < 4; i++)
                    w2buf[(tb + th * 4 + i) * 36 + o2] = fmaxf(a2[i], 0.f);
                // L3: 8 tokens @ [32][10], vectorized w2 reads, W3 in regs
                if (l < 40) {
                    #pragma unroll
                    for (int i = 0; i < 2; i++) {
                        const int tk = tb + tloc * 2 + i;
                        const v4f* wp = (const v4f*)&w2buf[tk * 36];
                        float a = b3o;
                        #pragma unroll
                        for (int q = 0; q < 8; q++) {
                            v4f w4 = wp[q];
                            a += w3r[4 * q]     * w4.x + w3r[4 * q + 1] * w4.y
                               + w3r[4 * q + 2] * w4.z + w3r[4 * q + 3] * w4.w;
                        }
                        const size_t oi = (size_t)(bb * SEQT + pw * 32 + tk) * NVOCAB + o3;
                        if (outbf) outb[oi] = f2bf(a); else outf[oi] = a;
                    }
                }
            }
            __syncthreads();
        }
    }
}

extern "C" void kernel_launch(void* const* d_in, const int* in_sizes, int n_in,
                              void* d_out, int out_size, void* d_ws, size_t ws_size,
                              hipStream_t stream) {
    const int* num1 = (const int*)d_in[0];
    const int* num2 = (const int*)d_in[1];
    float* ws = (float*)d_ws;

    hipLaunchKernelGGL(init_kernel, dim3(1), dim3(256), 0, stream,
                       d_in[2], d_in[3], d_in[4], d_in[5], d_in[6], d_in[7],
                       d_in[8], d_in[9], d_in[10], d_in[11], ws);
    hipLaunchKernelGGL(lstm_fused, dim3(BSZ), dim3(BLK), 0, stream,
                       num1, num2, ws, d_out);
}

// Round 9
// 1127.855 us; speedup vs baseline: 2.0937x; 2.0937x over previous
//
#include <hip/hip_runtime.h>
#include <hip/hip_bf16.h>

#define BSZ    256
#define SEQT   2048
#define NVOCAB 10
#define DEMB   32
#define G4     256
#define BLK    384   // 6 waves: 0,1 = recurrence; 2..5 = MLP (R0 shell, 920us)

typedef unsigned short u16;
typedef unsigned int   u32;
typedef float    v4f __attribute__((ext_vector_type(4)));
typedef u32      v4u __attribute__((ext_vector_type(4)));
typedef _Float16 v2h __attribute__((ext_vector_type(2)));
typedef _Float16 v8h __attribute__((ext_vector_type(8)));

// ws layout (float slots; some regions hold u32 f16-pair bits)
#define FLAG_OFF 0
#define XZ4_OFF  4                      // [10 v][64 j][4 g] f32 = 2560 (16B aligned)
#define WHP_OFF  (XZ4_OFF + 2560)      // u32 B-fragments [32 frag][64 lane][4 q] = 8192
#define W1P_OFF  (WHP_OFF + 8192)      // u32 [64 o][64 kpair] = 4096
#define W2P_OFF  (W1P_OFF + 4096)      // u32 [32 o][32 kpair] = 1024
#define W3_OFF   (W2P_OFF + 1024)      // f32 [32][10] = 320
#define B1_OFF   (W3_OFF + 320)
#define B2_OFF   (B1_OFF + 64)
#define B3_OFF   (B2_OFF + 32)

__device__ __forceinline__ float bf2f(u16 x) {
    union { u32 u; float f; } v; v.u = ((u32)x) << 16; return v.f;
}
__device__ __forceinline__ u16 f2bf(float f) {
    union { float f; u32 u; } v; v.f = f;
    u32 r = v.u + 0x7fff + ((v.u >> 16) & 1);
    return (u16)(r >> 16);
}
__device__ __forceinline__ float ldw(const void* p, int i, bool isbf) {
    return isbf ? bf2f(((const u16*)p)[i]) : ((const float*)p)[i];
}
__device__ __forceinline__ float frcp(float x) { return __builtin_amdgcn_rcpf(x); }
__device__ __forceinline__ float sigf(float z) { return frcp(1.f + __expf(-z)); }  // inf-safe
__device__ __forceinline__ u16 f2h(float x) {
    union { _Float16 h; u16 u; } v; v.h = (_Float16)x; return v.u;
}
__device__ __forceinline__ u32 packh2(float lo, float hi) {
    return (u32)f2h(lo) | ((u32)f2h(hi) << 16);
}
__device__ __forceinline__ float fdot2f(u32 a, u32 b, float c) {
    union { u32 u; v2h h; } ua, ub; ua.u = a; ub.u = b;
    return __builtin_amdgcn_fdot2(ua.h, ub.h, c, false);
}

// One-time prep: dtype detect, xz float4 table (E@Wx+b: 10 rows), MFMA
// B-fragment Wh table, f16-packed MLP weights.
__global__ void init_kernel(const void* __restrict__ E,  const void* __restrict__ Wx,
                            const void* __restrict__ Wh, const void* __restrict__ bg,
                            const void* __restrict__ W1, const void* __restrict__ b1,
                            const void* __restrict__ W2, const void* __restrict__ b2,
                            const void* __restrict__ W3, const void* __restrict__ b3,
                            float* __restrict__ ws) {
    __shared__ int s_isbf;
    const int tid = threadIdx.x;  // 256 threads, 1 block
    if (tid == 0) s_isbf = 1;
    __syncthreads();
    {   // bf16 data decodes small; fp32 low-halves decode wild exponents
        const u16* Eu = (const u16*)E;
        for (int i = tid; i < NVOCAB * DEMB; i += 256) {
            float v = bf2f(Eu[i]);
            if (!(fabsf(v) < 16.0f)) s_isbf = 0;
        }
    }
    __syncthreads();
    const bool isbf = (s_isbf != 0);
    if (tid == 0) ws[FLAG_OFF] = isbf ? 1.0f : 0.0f;
    u32* wsu = (u32*)ws;

    {   // xz[v][j][g] = b[g*64+j] + sum_d E[v][d]*Wx[d][g*64+j]  (float4 over g)
        const int g = tid >> 6, j = tid & 63, col = g * 64 + j;
        for (int v = 0; v < NVOCAB; v++) {
            float acc = ldw(bg, col, isbf);
            #pragma unroll
            for (int d = 0; d < DEMB; d++)
                acc += ldw(E, v * DEMB + d, isbf) * ldw(Wx, d * G4 + col, isbf);
            ws[XZ4_OFF + (v * 64 + j) * 4 + g] = acc;
        }
    }
    // MFMA B-fragment Wh table for mfma_f32_16x16x32_f16:
    //   frag f = (t,kk): col-tile t (16 cols each), k-half kk (K=32).
    //   lane holds B[k = kk*32 + (lane>>4)*8 + 2q + {0,1}][col = t*16 + (lane&15)]
    //   as f16 pair in u32 q of the fragment.  B[k][c] = Wh[k][c].
    //   index = (f*64 + lane)*4 + q
    for (int i = tid; i < 8192; i += 256) {
        int f = i >> 8, rem = i & 255, lane = rem >> 2, q = rem & 3;
        int t = f >> 1, kk = f & 1;
        int c  = t * 16 + (lane & 15);
        int k0 = kk * 32 + (lane >> 4) * 8 + 2 * q;
        wsu[WHP_OFF + i] = packh2(ldw(Wh, k0 * G4 + c, isbf),
                                  ldw(Wh, (k0 + 1) * G4 + c, isbf));
    }
    for (int i = tid; i < 4096; i += 256) {   // W1 [128][64] -> [o][kpair] f16x2
        int o = i >> 6, kk = i & 63;
        wsu[W1P_OFF + i] = packh2(ldw(W1, (2 * kk) * 64 + o, isbf),
                                  ldw(W1, (2 * kk + 1) * 64 + o, isbf));
    }
    for (int i = tid; i < 1024; i += 256) {   // W2 [64][32] -> [o][kpair]
        int o = i >> 5, kk = i & 31;
        wsu[W2P_OFF + i] = packh2(ldw(W2, (2 * kk) * 32 + o, isbf),
                                  ldw(W2, (2 * kk + 1) * 32 + o, isbf));
    }
    for (int i = tid; i < 320; i += 256) ws[W3_OFF + i] = ldw(W3, i, isbf);
    if (tid < 64) ws[B1_OFF + tid] = ldw(b1, tid, isbf);
    if (tid < 32) ws[B2_OFF + tid] = ldw(b2, tid, isbf);
    if (tid < NVOCAB) ws[B3_OFF + tid] = ldw(b3, tid, isbf);
}

// One block (384 thr, 6 waves) per batch element; waves 0,1 = rec, 2..5 = MLP.
// Recurrence via MFMA: z^T = h^T x Wh as D = A.B per 16-col tile.
//   A[16][32]: every lane loads the SAME h slice (addr depends only on l>>4)
//     -> all 16 A-rows identical -> all D-rows identical -> row-map immune.
//   B[32][16] = Wh tile, staged by init as AGPR-resident fragments.  The
//     allocator's AGPR demotion (the ~500 junk cyc/step of the fdot2 design:
//     v_dot2 can't source AGPRs, VGPR budget pinned at 84 across
//     launch_bounds/waves_per_eu/num_vgpr) is FREE here: MFMA reads AGPRs
//     natively.
//   D col = lane&15 (m89-verified); within-lane k-permutation cancels
//     between A and B (same packing formula both sides).
//   z[g*64+l] = acc[g*4 + (l>>4)].x in lane l's OWN registers ->
//     gate inputs via 3 v_cndmask each, NO LDS redistribution.
__global__ __launch_bounds__(BLK, 2) void lstm_fused(
    const int* __restrict__ num1, const int* __restrict__ num2,
    const float* __restrict__ ws, void* __restrict__ outv)
{
    __shared__ __align__(16) float xz4s[2560];          // 10240 B
    __shared__ __align__(16) u16 hwinh[2][32][128];     // 16384 B (f16 h, dbuf window)
    __shared__ __align__(16) u32 W1p[64 * 68];          // 17408 B
    __shared__ __align__(16) u32 W2p[32 * 36];          //  4608 B
    __shared__ float W3s[320];                          //  1280 B
    __shared__ __align__(16) u16 w1h[32 * 72];          //  4608 B
    __shared__ __align__(16) float w2buf[32 * 36];      //  4608 B
    __shared__ int idxs[2][2][32];                      //   512 B  -> ~59.6 KB

    const int tid = threadIdx.x, bb = blockIdx.x;
    const int wv = tid >> 6, l = tid & 63;
    const u32* wsu = (const u32*)ws;
    const bool outbf = (ws[FLAG_OFF] != 0.0f);

    for (int i = tid; i < 2560; i += BLK) xz4s[i] = ws[XZ4_OFF + i];
    for (int i = tid; i < 4096; i += BLK) { int o = i >> 6, kk = i & 63; W1p[o * 68 + kk] = wsu[W1P_OFF + i]; }
    for (int i = tid; i < 1024; i += BLK) { int o = i >> 5, kk = i & 31; W2p[o * 36 + kk] = wsu[W2P_OFF + i]; }
    for (int i = tid; i < 320; i += BLK) W3s[i] = ws[W3_OFF + i];
    if (tid < 128) hwinh[1][31][tid] = 0;               // h_{-1} = 0 (f16 zero)
    if (tid < 64) { int c0 = tid >> 5, tt = tid & 31;
                    idxs[0][c0][tt] = (c0 == 0 ? num1 : num2)[bb * SEQT + tt]; }

    if (wv < 2) {
        // -------- recurrence wave: chain wv, lane l = unit --------
        const int ch = wv;
        // 32 Wh B-fragments, loop-invariant; let the allocator park them in
        // AGPRs (its preference) — MFMA sources them there without copies.
        union u2h { v4u u; v8h h; };
        v8h bq[32];
        {
            const v4u* bsrc = (const v4u*)(wsu + WHP_OFF);
            #pragma unroll
            for (int f = 0; f < 32; f++) { u2h cv; cv.u = bsrc[f * 64 + l]; bq[f] = cv.h; }
        }
        float c = 0.f;
        __syncthreads();
        for (int win = 0; win <= 64; win++) {
            if (win < 64) {
                const int wb = win & 1;
                #pragma unroll 1
                for (int tt = 0; tt < 32; tt++) {
                    const int idx  = idxs[wb][ch][tt];
                    const int rbuf = (tt == 0) ? 1 - wb : wb;
                    const int rrow = (tt + 31) & 31;
                    // A fragments: h slice per lane group (broadcast across l&15)
                    const v4u* hpA = (const v4u*)&hwinh[rbuf][rrow][ch * 64];
                    u2h a0c, a1c;
                    a0c.u = hpA[l >> 4];          // k = 0..31 slice
                    a1c.u = hpA[4 + (l >> 4)];    // k = 32..63 slice
                    v4f xzv = *(const v4f*)&xz4s[(idx * 64 + l) * 4];
                    v4f acc[16];
                    #pragma unroll
                    for (int t = 0; t < 16; t++) {
                        v4f z4 = {0.f, 0.f, 0.f, 0.f};
                        z4 = __builtin_amdgcn_mfma_f32_16x16x32_f16(a0c.h, bq[2 * t],     z4, 0, 0, 0);
                        z4 = __builtin_amdgcn_mfma_f32_16x16x32_f16(a1c.h, bq[2 * t + 1], z4, 0, 0, 0);
                        acc[t] = z4;
                    }
                    const int grp = l >> 4;
                    float zi = (grp == 0) ? acc[0].x  : (grp == 1) ? acc[1].x  : (grp == 2) ? acc[2].x  : acc[3].x;
                    float zf = (grp == 0) ? acc[4].x  : (grp == 1) ? acc[5].x  : (grp == 2) ? acc[6].x  : acc[7].x;
                    float zg = (grp == 0) ? acc[8].x  : (grp == 1) ? acc[9].x  : (grp == 2) ? acc[10].x : acc[11].x;
                    float zo = (grp == 0) ? acc[12].x : (grp == 1) ? acc[13].x : (grp == 2) ? acc[14].x : acc[15].x;
                    zi += xzv.x; zf += xzv.y; zg += xzv.z; zo += xzv.w;
                    float gi = sigf(zi), gf = sigf(zf);
                    float gG = 2.f * sigf(2.f * zg) - 1.f, go = sigf(zo);
                    c = gf * c + gi * gG;
                    float th = 1.f - 2.f * frcp(__expf(2.f * c) + 1.f);  // inf-safe tanh
                    hwinh[wb][tt][ch * 64 + l] = f2h(go * th);
                    // same-wave DS ordering: next step's read needs no barrier
                }
            }
            __syncthreads();
        }
    } else {
        // -------- MLP wave mw = wv-2: tokens [8*mw, 8*mw+8) of previous window ----
        const int mw = wv - 2;
        const int tb = mw * 8;
        const float b1o = ws[B1_OFF + l];
        const int th = l >> 5, o2 = l & 31;
        const float b2o = ws[B2_OFF + o2];
        const int tloc = l / 10, o3 = l - tloc * 10;
        const float b3o = (l < 40) ? ws[B3_OFF + o3] : 0.f;
        u16* outb = (u16*)outv; float* outf = (float*)outv;
        __syncthreads();
        // hoist W3 column into registers (loop-invariant)
        float w3r[32];
        #pragma unroll
        for (int k = 0; k < 32; k++) w3r[k] = (l < 40) ? W3s[k * 10 + o3] : 0.f;
        for (int win = 0; win <= 64; win++) {
            if (win < 63 && mw < 2 && l < 32)   // waves 2,3 prefetch next idx window
                idxs[(win + 1) & 1][mw][l] =
                    (mw == 0 ? num1 : num2)[bb * SEQT + (win + 1) * 32 + l];
            if (win >= 1) {
                const int pw = win - 1, pwb = pw & 1;
                // L1: relu(b1 + hwin[tk][:128] . W1[:,l]), 8 tokens/wave
                float acc[8];
                #pragma unroll
                for (int i = 0; i < 8; i++) acc[i] = b1o;
                for (int kc = 0; kc < 16; kc++) {
                    v4u wq = *(const v4u*)&W1p[l * 68 + 4 * kc];
                    #pragma unroll
                    for (int i = 0; i < 8; i++) {
                        v4u hq = *(const v4u*)&hwinh[pwb][tb + i][8 * kc];
                        float a = acc[i];
                        a = fdot2f(wq.x, hq.x, a); a = fdot2f(wq.y, hq.y, a);
                        a = fdot2f(wq.z, hq.z, a); a = fdot2f(wq.w, hq.w, a);
                        acc[i] = a;
                    }
                }
                #pragma unroll
                for (int i = 0; i < 8; i++)
                    w1h[(tb + i) * 72 + l] = f2h(fmaxf(acc[i], 0.f));
                // L2: own-wave rows, same-wave LDS ordering (no barrier)
                float a2[4];
                #pragma unroll
                for (int i = 0; i < 4; i++) a2[i] = b2o;
                for (int kc = 0; kc < 8; kc++) {
                    v4u wq = *(const v4u*)&W2p[o2 * 36 + 4 * kc];
                    #pragma unroll
                    for (int i = 0; i < 4; i++) {
                        v4u hq = *(const v4u*)&w1h[(tb + th * 4 + i) * 72 + 8 * kc];
                        float a = a2[i];
                        a = fdot2f(wq.x, hq.x, a); a = fdot2f(wq.y, hq.y, a);
                        a = fdot2f(wq.z, hq.z, a); a = fdot2f(wq.w, hq.w, a);
                        a2[i] = a;
                    }
                }
                #pragma unroll
                for (int i = 0; i < 4; i++)
                    w2buf[(tb + th * 4 + i) * 36 + o2] = fmaxf(a2[i], 0.f);
                // L3: 8 tokens @ [32][10], vectorized w2 reads, W3 in regs
                if (l < 40) {
                    #pragma unroll
                    for (int i = 0; i < 2; i++) {
                        const int tk = tb + tloc * 2 + i;
                        const v4f* wp = (const v4f*)&w2buf[tk * 36];
                        float a = b3o;
                        #pragma unroll
                        for (int q = 0; q < 8; q++) {
                            v4f w4 = wp[q];
                            a += w3r[4 * q]     * w4.x + w3r[4 * q + 1] * w4.y
                               + w3r[4 * q + 2] * w4.z + w3r[4 * q + 3] * w4.w;
                        }
                        const size_t oi = (size_t)(bb * SEQT + pw * 32 + tk) * NVOCAB + o3;
                        if (outbf) outb[oi] = f2bf(a); else outf[oi] = a;
                    }
                }
            }
            __syncthreads();
        }
    }
}

extern "C" void kernel_launch(void* const* d_in, const int* in_sizes, int n_in,
                              void* d_out, int out_size, void* d_ws, size_t ws_size,
                              hipStream_t stream) {
    const int* num1 = (const int*)d_in[0];
    const int* num2 = (const int*)d_in[1];
    float* ws = (float*)d_ws;

    hipLaunchKernelGGL(init_kernel, dim3(1), dim3(256), 0, stream,
                       d_in[2], d_in[3], d_in[4], d_in[5], d_in[6], d_in[7],
                       d_in[8], d_in[9], d_in[10], d_in[11], ws);
    hipLaunchKernelGGL(lstm_fused, dim3(BSZ), dim3(BLK), 0, stream,
                       num1, num2, ws, d_out);
}